// Round 1
// baseline (131.180 us; speedup 1.0000x reference)
//
#include <hip/hip_runtime.h>
#include <cstdint>

typedef float  f32x4 __attribute__((ext_vector_type(4)));
typedef short  s16x8 __attribute__((ext_vector_type(8)));

__device__ __forceinline__ unsigned short f2bf(float f){
  unsigned int u = __float_as_uint(f);
  unsigned int r = (u + 0x7FFFu + ((u >> 16) & 1u)) >> 16;   // RNE
  return (unsigned short)r;
}

// weights re-laid as bf16: g_Wt[s][o][c], s = (kh*3+kw)*2 + h, value = w[o][h*32+c][kh][kw]
__device__ alignas(16) unsigned short g_Wt[18*64*32];

__global__ void wt_kernel(const float* __restrict__ w){
  int t = blockIdx.x*256 + threadIdx.x;
  if (t >= 18*64*32) return;
  int c = t & 31, o = (t >> 5) & 63, s = t >> 11;
  int h = s & 1, tap = s >> 1, kh = tap/3, kw = tap%3;
  int ci = h*32 + c;
  g_Wt[t] = f2bf(w[((o*64 + ci)*3 + kh)*3 + kw]);
}

#define COLS 130

__global__ __launch_bounds__(256) void conv_main(const float* __restrict__ x,
                                                 const float* __restrict__ bias,
                                                 float* __restrict__ out){
  // LDS x-tile: [r=3][col=130][ci=64] bf16, byte = (r*COLS+col)*128 + ci*2, XOR-swizzled ^((col&7)<<4)
  __shared__ alignas(16) char smem[3*COLS*64*2];
  const int half = blockIdx.x, y = blockIdx.y, b = blockIdx.z;
  const int tid = threadIdx.x;
  const int n0 = half*128;
  const float* xb = x + (size_t)b*64*65536;

  // ---- stage: fp32 -> bf16, transpose to ci-innermost ----
  // tasks: [r:3][col-quad q:33][ci-pair cp:32]  (cp lane-major -> conflict-free ds_write_b32)
  for (int it = 0; it < 13; ++it){
    int tau = it*256 + tid;
    if (tau < 3168){
      int cp = tau & 31;
      int rq = tau >> 5;
      int q = rq % 33, r = rq / 33;
      int ci = cp*2;
      int cg = n0 + q*4; if (cg > 252) cg = 252;   // clamp: clamped cols only feed discarded n>=254
      const float* p0 = xb + ((size_t)ci*256 + (y+r))*256 + cg;
      float4 v0 = *reinterpret_cast<const float4*>(p0);
      float4 v1 = *reinterpret_cast<const float4*>(p0 + 65536);
      const float* a0 = reinterpret_cast<const float*>(&v0);
      const float* a1 = reinterpret_cast<const float*>(&v1);
      int c0 = q*4;
      #pragma unroll
      for (int j = 0; j < 4; ++j){
        int c = c0 + j;
        if (c < COLS){
          unsigned int pk = (unsigned int)f2bf(a0[j]) | ((unsigned int)f2bf(a1[j]) << 16);
          int off = (((r*COLS + c)*64 + ci)*2) ^ ((c & 7) << 4);
          *reinterpret_cast<unsigned int*>(smem + off) = pk;
        }
      }
    }
  }
  __syncthreads();

  // ---- compute: wave wv owns Cout rows [wv*16, wv*16+16), all 8 n-tiles ----
  const int lane = tid & 63, wv = tid >> 6;
  const int lc = lane & 15, g = lane >> 4;
  f32x4 acc[8];
  #pragma unroll
  for (int i = 0; i < 8; ++i) acc[i] = (f32x4){0.f,0.f,0.f,0.f};

  #pragma unroll
  for (int kh = 0; kh < 3; ++kh){
    #pragma unroll
    for (int kw = 0; kw < 3; ++kw){
      #pragma unroll
      for (int h = 0; h < 2; ++h){
        const int s = (kh*3 + kw)*2 + h;
        // A frag: W[o = wv*16 + lc][k = h*32 + g*8 + e]
        s16x8 afrag = *reinterpret_cast<const s16x8*>(&g_Wt[(s*64 + wv*16 + lc)*32 + g*8]);
        #pragma unroll
        for (int nt = 0; nt < 8; ++nt){
          int col = nt*16 + lc + kw;               // local input col for output n = n0+nt*16+lc
          int off = ((kh*COLS + col)*128 + h*64 + g*16) ^ ((col & 7) << 4);
          s16x8 bfrag = *reinterpret_cast<const s16x8*>(smem + off);
          acc[nt] = __builtin_amdgcn_mfma_f32_16x16x32_bf16(afrag, bfrag, acc[nt], 0, 0, 0);
        }
      }
    }
  }

  // ---- epilogue: D row = 4*g + j (within wave's 16 Couts), col = lc ----
  const int ob = wv*16 + g*4;
  const float bv0 = bias[ob], bv1 = bias[ob+1], bv2 = bias[ob+2], bv3 = bias[ob+3];
  #pragma unroll
  for (int nt = 0; nt < 8; ++nt){
    int n = n0 + nt*16 + lc;
    if (n < 254){
      size_t base = (((size_t)b*64 + ob)*254 + y)*254 + n;
      out[base]            = acc[nt][0] + bv0;
      out[base +   64516]  = acc[nt][1] + bv1;
      out[base + 2*64516]  = acc[nt][2] + bv2;
      out[base + 3*64516]  = acc[nt][3] + bv3;
    }
  }
}

extern "C" void kernel_launch(void* const* d_in, const int* in_sizes, int n_in,
                              void* d_out, int out_size, void* d_ws, size_t ws_size,
                              hipStream_t stream) {
  const float* x    = (const float*)d_in[0];
  const float* wgt  = (const float*)d_in[1];
  const float* bias = (const float*)d_in[2];
  float* out = (float*)d_out;

  wt_kernel<<<144, 256, 0, stream>>>(wgt);
  conv_main<<<dim3(2, 254, 8), 256, 0, stream>>>(x, bias, out);
}

// Round 3
// 92.849 us; speedup vs baseline: 1.4128x; 1.4128x over previous
//
#include <hip/hip_runtime.h>
#include <cstdint>

typedef float  f32x4  __attribute__((ext_vector_type(4)));
typedef float  f32x16 __attribute__((ext_vector_type(16)));
typedef short  s16x8  __attribute__((ext_vector_type(8)));

__device__ __forceinline__ unsigned short f2bf(float f){
  unsigned int u = __float_as_uint(f);
  return (unsigned short)((u + 0x7FFFu + ((u >> 16) & 1u)) >> 16);   // RNE
}

// g_Wt[tap][o][ci] bf16, tap = kh*3+kw : W[o][ci][kh][kw]
__device__ alignas(16) unsigned short g_Wt[9*64*64];

__global__ void wt_kernel(const float* __restrict__ w){
  int t = blockIdx.x*256 + threadIdx.x;          // 36864 total
  if (t >= 9*64*64) return;
  int ci = t & 63, o = (t >> 6) & 63, tap = t >> 12;
  int kh = tap/3, kw = tap%3;
  g_Wt[t] = f2bf(w[((o*64 + ci)*3 + kh)*3 + kw]);
}

#define SLAB 8448   // 66 cols * 64 ci * 2B; swizzle: (full byte offset) ^ ((col&7)<<4)

__global__ __launch_bounds__(256, 2) void conv_main(const float* __restrict__ x,
                                                    const float* __restrict__ bias,
                                                    float* __restrict__ out){
  __shared__ alignas(16) char smem[4*SLAB];
  const int quarter = blockIdx.x;      // n0 = quarter*64
  const int ystrip  = blockIdx.y;      // y0 = ystrip*8
  const int b       = blockIdx.z;
  const int n0 = quarter*64, y0 = ystrip*8;
  const int tid = threadIdx.x, lane = tid & 63, wv = tid >> 6;
  const int wr = wv >> 1, wc = wv & 1;
  const float* xb = x + (size_t)b*64*65536;

  // ---- hoisted A fragments: aw[tap*4+part], constant across all rows ----
  s16x8 aw[36];
  {
    const int o = wr*32 + (lane & 31);
    const int cib = (lane >> 5) * 8;
    #pragma unroll
    for (int tap = 0; tap < 9; ++tap)
      #pragma unroll
      for (int part = 0; part < 4; ++part)
        aw[tap*4+part] = *reinterpret_cast<const s16x8*>(
            &g_Wt[(tap*64 + o)*64 + part*16 + cib]);
  }

  // ---- hoisted bias (C/D row map: o = wr*32 + 4*(lane>>5) + (reg&3)+8*(reg>>2)) ----
  const int ob = wr*32 + 4*(lane >> 5);
  float bv[16];
  #pragma unroll
  for (int reg = 0; reg < 16; ++reg)
    bv[reg] = bias[ob + (reg & 3) + 8*(reg >> 2)];

  // ---- prologue: stage input rows y0, y0+1, y0+2 into slots 0,1,2 ----
  #pragma unroll
  for (int r = 0; r < 3; ++r){
    const int rr = y0 + r;                       // <= 250, in range
    char* slab = smem + r*SLAB;
    #pragma unroll
    for (int it = 0; it < 3; ++it){
      int tau = it*256 + tid;
      if (tau < 544){                            // 17 quads x 32 ci-pairs
        int cp = tau & 31, q = tau >> 5, c0 = q*4;
        int cg = n0 + c0; if (cg > 252) cg = 252;     // clamped cols feed only discarded n>=254
        const float* p = xb + (size_t)(2*cp)*65536 + rr*256 + cg;
        float4 v0 = *reinterpret_cast<const float4*>(p);
        float4 v1 = *reinterpret_cast<const float4*>(p + 65536);
        const float* a0 = reinterpret_cast<const float*>(&v0);
        const float* a1 = reinterpret_cast<const float*>(&v1);
        #pragma unroll
        for (int j = 0; j < 4; ++j){
          int c = c0 + j;
          if (c < 66){
            unsigned int pk = (unsigned)f2bf(a0[j]) | ((unsigned)f2bf(a1[j]) << 16);
            *reinterpret_cast<unsigned int*>(slab + ((c*128 + cp*4) ^ ((c & 7) << 4))) = pk;
          }
        }
      }
    }
  }
  __syncthreads();

  // ---- rolling loop: 8 output rows, ring of 4 slabs ----
  for (int yloc = 0; yloc < 8; ++yloc){
    const int y = y0 + yloc;

    // T14 issue-early: global loads for input row y+3 into regs
    float4 p0[3], p1[3];
    if (yloc < 7){
      int rr = y + 3; if (rr > 255) rr = 255;
      #pragma unroll
      for (int it = 0; it < 3; ++it){
        int tau = it*256 + tid;
        if (tau < 544){
          int cp = tau & 31, q = tau >> 5;
          int cg = n0 + q*4; if (cg > 252) cg = 252;
          const float* p = xb + (size_t)(2*cp)*65536 + rr*256 + cg;
          p0[it] = *reinterpret_cast<const float4*>(p);
          p1[it] = *reinterpret_cast<const float4*>(p + 65536);
        }
      }
    }

    // compute output row y from ring slots (yloc+kh)&3
    if (y < 254){
      f32x16 acc;
      #pragma unroll
      for (int i = 0; i < 16; ++i) acc[i] = 0.f;

      #pragma unroll
      for (int kh = 0; kh < 3; ++kh){
        const char* slab = smem + ((yloc + kh) & 3)*SLAB;
        #pragma unroll
        for (int kw = 0; kw < 3; ++kw){
          const int col = wc*32 + (lane & 31) + kw;
          const int swz = (col & 7) << 4;
          const int cb  = col*128 + ((lane >> 5) << 4);
          #pragma unroll
          for (int part = 0; part < 4; ++part){
            s16x8 bf = *reinterpret_cast<const s16x8*>(
                slab + ((cb + part*32) ^ swz));
            acc = __builtin_amdgcn_mfma_f32_32x32x16_bf16(aw[(kh*3+kw)*4 + part], bf, acc, 0, 0, 0);
          }
        }
      }

      // store: col = lane&31 within wave tile, row per C/D map
      const int nl = n0 + wc*32 + (lane & 31);
      if (nl < 254){
        size_t rowbase = (((size_t)b*64 + ob)*254 + y)*254 + nl;
        #pragma unroll
        for (int reg = 0; reg < 16; ++reg){
          int od = (reg & 3) + 8*(reg >> 2);
          out[rowbase + (size_t)od*64516] = acc[reg] + bv[reg];
        }
      }
    }

    // write-late: convert + ds_write row y+3 into slot (yloc+3)&3
    if (yloc < 7){
      char* slab = smem + ((yloc + 3) & 3)*SLAB;
      #pragma unroll
      for (int it = 0; it < 3; ++it){
        int tau = it*256 + tid;
        if (tau < 544){
          int cp = tau & 31, q = tau >> 5, c0 = q*4;
          const float* a0 = reinterpret_cast<const float*>(&p0[it]);
          const float* a1 = reinterpret_cast<const float*>(&p1[it]);
          #pragma unroll
          for (int j = 0; j < 4; ++j){
            int c = c0 + j;
            if (c < 66){
              unsigned int pk = (unsigned)f2bf(a0[j]) | ((unsigned)f2bf(a1[j]) << 16);
              *reinterpret_cast<unsigned int*>(slab + ((c*128 + cp*4) ^ ((c & 7) << 4))) = pk;
            }
          }
        }
      }
    }
    __syncthreads();
  }
}

extern "C" void kernel_launch(void* const* d_in, const int* in_sizes, int n_in,
                              void* d_out, int out_size, void* d_ws, size_t ws_size,
                              hipStream_t stream) {
  const float* x    = (const float*)d_in[0];
  const float* wgt  = (const float*)d_in[1];
  const float* bias = (const float*)d_in[2];
  float* out = (float*)d_out;

  wt_kernel<<<144, 256, 0, stream>>>(wgt);
  conv_main<<<dim3(4, 32, 8), 256, 0, stream>>>(x, bias, out);
}